// Round 1
// 1112.711 us; speedup vs baseline: 1.1520x; 1.1520x over previous
//
#include <hip/hip_runtime.h>
#include <math.h>

#define L_TOK 69120
#define C_DIM 384
#define C3 1152
#define C4 1536
#define N_TOK 120
#define N_HEAD 12
#define BIAS_ROWS 2736
#define WH 6912
#define CHUNK 13824
#define NCHUNK 5

typedef __attribute__((ext_vector_type(8))) short short8;
typedef __attribute__((ext_vector_type(4))) float floatx4;

__device__ __forceinline__ unsigned short f2bf(float f) {
    union { float f; unsigned int u; } c; c.f = f;
    unsigned int u = c.u;
    return (unsigned short)((u + 0x7fffu + ((u >> 16) & 1u)) >> 16);
}
__device__ __forceinline__ float bf2f(unsigned short s) {
    union { unsigned int u; float f; } c; c.u = ((unsigned int)s) << 16;
    return c.f;
}

__device__ __forceinline__ void gl_lds16(const void* g, void* l) {
    __builtin_amdgcn_global_load_lds((const __attribute__((address_space(1))) unsigned int*)g,
                                     (__attribute__((address_space(3))) unsigned int*)l, 16, 0, 0);
}

// window-order row m = w_idx*120 + n  ->  global token index
__device__ __forceinline__ int win_to_global(int m) {
    int w_idx = m / N_TOK;
    int n = m - w_idx * N_TOK;
    int zw = w_idx / 144;
    int rem = w_idx - zw * 144;
    int hw = rem / 18;
    int ww = rem - hw * 18;
    int zl = n / 60;
    int r2 = n - zl * 60;
    int hl = r2 / 10;
    int wl = r2 - hl * 10;
    return ((zw * 2 + zl) * 48 + hw * 6 + hl) * 180 + ww * 10 + wl;
}

// -------- weight transpose+convert: W (K x N fp32) -> WT (N x K bf16) --------
__global__ __launch_bounds__(256) void k_wt(const float* __restrict__ W,
                                            unsigned short* __restrict__ WT, int K, int N) {
    __shared__ float tle[32][33];
    int n0 = blockIdx.x << 5, k0 = blockIdx.y << 5;
    for (int i = threadIdx.y; i < 32; i += 8)
        tle[i][threadIdx.x] = W[(size_t)(k0 + i) * N + n0 + threadIdx.x];
    __syncthreads();
    for (int i = threadIdx.y; i < 32; i += 8)
        WT[(size_t)(n0 + i) * K + k0 + threadIdx.x] = f2bf(tle[threadIdx.x][i]);
}

// -------- bias transpose: (2736 x 6912 fp32) -> (6912 x 2736 bf16) --------
__global__ __launch_bounds__(256) void k_bt(const float* __restrict__ Bsrc,
                                            unsigned short* __restrict__ BTt) {
    __shared__ float tle[32][33];
    int c0 = blockIdx.x << 5;
    int r0 = blockIdx.y << 5;
    for (int i = threadIdx.y; i < 32; i += 8) {
        int r = r0 + i;
        if (r < BIAS_ROWS) tle[i][threadIdx.x] = Bsrc[(size_t)r * WH + c0 + threadIdx.x];
    }
    __syncthreads();
    int rr = r0 + threadIdx.x;
    if (rr < BIAS_ROWS)
        for (int i = threadIdx.y; i < 32; i += 8)
            BTt[(size_t)(c0 + i) * BIAS_ROWS + rr] = f2bf(tle[threadIdx.x][i]);
}

// -------- x -> window-permuted bf16 (one pass; kills 9x fp32 refetch+convert) ----
// block = 4 rows (one per wave); lane covers 6 consecutive floats.
__global__ __launch_bounds__(256) void k_xc(const float* __restrict__ x,
                                            unsigned short* __restrict__ xb) {
    const int m = (blockIdx.x << 2) + (threadIdx.x >> 6);
    const int lane = threadIdx.x & 63;
    const float* src = x + (size_t)win_to_global(m) * C_DIM + lane * 6;
    unsigned short* dst = xb + (size_t)m * C_DIM + lane * 6;
    float2 a = *(const float2*)(src);
    float2 b = *(const float2*)(src + 2);
    float2 c = *(const float2*)(src + 4);
    unsigned int u0 = (unsigned int)f2bf(a.x) | ((unsigned int)f2bf(a.y) << 16);
    unsigned int u1 = (unsigned int)f2bf(b.x) | ((unsigned int)f2bf(b.y) << 16);
    unsigned int u2 = (unsigned int)f2bf(c.x) | ((unsigned int)f2bf(c.y) << 16);
    *(unsigned int*)(dst) = u0;
    *(unsigned int*)(dst + 2) = u1;
    *(unsigned int*)(dst + 4) = u2;
}

// -------- shared MFMA mainloop (bf16 A, bf16 B^T, both via global_load_lds) --------
template <int K>
__device__ __forceinline__ void mfma_loop(const unsigned short* __restrict__ A,
                                          const unsigned short* __restrict__ BT,
                                          unsigned short* As, unsigned short* Bs,
                                          int m0, int n0, floatx4 acc[4][4]) {
    const int tid = threadIdx.x;
    const int wave = tid >> 6, lane = tid & 63;
    const int wm = (wave >> 1) << 6, wn = (wave & 1) << 6;
    const int lm = lane & 15, lq = lane >> 4;
    const int srow = lane >> 2, scol = (lane & 3) << 3;
    const unsigned short* ags = A + (size_t)(m0 + wave * 32 + srow) * K + scol;
    const unsigned short* bgs = BT + (size_t)(n0 + wave * 32 + srow) * K + scol;
    char* lA = (char*)As + wave * 2048;
    char* lB = (char*)Bs + wave * 2048;
    for (int kk = 0; kk < K; kk += 32) {
        gl_lds16(ags + kk, lA);
        gl_lds16(ags + (size_t)16 * K + kk, lA + 1024);
        gl_lds16(bgs + kk, lB);
        gl_lds16(bgs + (size_t)16 * K + kk, lB + 1024);
        __syncthreads();
        short8 af[4], bq[4];
#pragma unroll
        for (int i = 0; i < 4; ++i) af[i] = *(const short8*)(As + (wm + i * 16 + lm) * 32 + lq * 8);
#pragma unroll
        for (int j = 0; j < 4; ++j) bq[j] = *(const short8*)(Bs + (wn + j * 16 + lm) * 32 + lq * 8);
#pragma unroll
        for (int i = 0; i < 4; ++i)
#pragma unroll
            for (int j = 0; j < 4; ++j)
                acc[i][j] = __builtin_amdgcn_mfma_f32_16x16x32_bf16(af[i], bq[j], acc[i][j], 0, 0, 0);
        __syncthreads();
    }
}

// -------- K1: qkv MFMA GEMM on pre-permuted bf16 A --------
// q: (wh, n, d) scaled; k: (wh, n, d); v: TRANSPOSED (wh, d, n) for attn B-frags
__global__ __launch_bounds__(256) void k_qkv(const unsigned short* __restrict__ xb,
                                             const unsigned short* __restrict__ wqkvT,
                                             const float* __restrict__ bqkv,
                                             unsigned short* __restrict__ q,
                                             unsigned short* __restrict__ kbuf,
                                             unsigned short* __restrict__ vbuf) {
    __shared__ unsigned short As[128 * 32];
    __shared__ unsigned short Bs[128 * 32];
    const int tid = threadIdx.x;
    const int wave = tid >> 6, lane = tid & 63;
    const int wm = (wave >> 1) << 6, wn = (wave & 1) << 6;
    const int lm = lane & 15, lq = lane >> 4;
    const int m0 = blockIdx.y << 7, n0 = blockIdx.x << 7;
    floatx4 acc[4][4];
#pragma unroll
    for (int i = 0; i < 4; ++i)
#pragma unroll
        for (int j = 0; j < 4; ++j) acc[i][j] = (floatx4){0.f, 0.f, 0.f, 0.f};
    mfma_loop<C_DIM>(xb, wqkvT, As, Bs, m0, n0, acc);

    const int sel = n0 / C_DIM;   // uniform: 128 | 384
    unsigned short* dst = (sel == 0) ? q : (sel == 1) ? kbuf : vbuf;
    const float scl = (sel == 0) ? 0.17677669529663687f : 1.0f;
#pragma unroll
    for (int i = 0; i < 4; ++i) {
        int rowb = m0 + wm + i * 16 + lq * 4;
        int wi[4], nn[4];
#pragma unroll
        for (int r = 0; r < 4; ++r) {
            int row = rowb + r;
            wi[r] = row / N_TOK;
            nn[r] = row - wi[r] * N_TOK;
        }
#pragma unroll
        for (int j = 0; j < 4; ++j) {
            int colg = n0 + wn + j * 16 + lm;
            float bias = bqkv[colg];
            int c2 = colg - sel * C_DIM;
            int head = c2 >> 5, dd = c2 & 31;
#pragma unroll
            for (int r = 0; r < 4; ++r) {
                unsigned short val = f2bf((acc[i][j][r] + bias) * scl);
                if (sel == 2)
                    dst[((size_t)(wi[r] * N_HEAD + head) * 32 + dd) * N_TOK + nn[r]] = val;
                else
                    dst[(((size_t)(wi[r] * N_HEAD + head) * N_TOK + nn[r]) << 5) + dd] = val;
            }
        }
    }
}

// -------- K2: MFMA windowed attention (S^T = K·Q^T trick) --------
// block = one (window, head), 4 waves; wave handles q-tiles {wave, wave+4}.
// S^T C-layout: lane holds query col=lane&15, keys rows quad*4+reg (+16*kt)
// -> softmax = in-lane reduce + shfl_xor(16,32). P via per-wave LDS -> A-frags.
__global__ __launch_bounds__(256) void k_attn(const unsigned short* __restrict__ q,
                                              const unsigned short* __restrict__ k,
                                              const unsigned short* __restrict__ vt,
                                              const unsigned short* __restrict__ btabT,
                                              unsigned short* __restrict__ ao) {
    const int wh = blockIdx.x;
    const int w = wh / N_HEAD;
    const int h = wh - w * N_HEAD;
    __shared__ float blds[BIAS_ROWS];
    __shared__ __align__(16) unsigned short plds[4][16 * 136];
    const int tid = threadIdx.x;
    const unsigned short* bptr = btabT + (size_t)wh * BIAS_ROWS;
    for (int i = tid; i < BIAS_ROWS; i += 256) blds[i] = bf2f(bptr[i]);
    __syncthreads();

    const int wave = tid >> 6, lane = tid & 63;
    const int lm = lane & 15, lq = lane >> 4;
    const unsigned short* kwh = k + (size_t)wh * N_TOK * 32;
    const unsigned short* qwh = q + (size_t)wh * N_TOK * 32;
    const unsigned short* vwh = vt + (size_t)wh * 32 * N_TOK;
    unsigned short* pl = plds[wave];

    // K A-fragments, reused for both q-tiles (keys 16kt+lm, d = lq*8..+7)
    short8 kfr[8];
#pragma unroll
    for (int kt = 0; kt < 8; ++kt)
        kfr[kt] = *(const short8*)(kwh + (size_t)(kt * 16 + lm) * 32 + lq * 8);

    // bias key-offsets: depend only on (kt, lq); reg deltas -1,-2,-3 with
    // w2-wrap (+123 step) when k0%10==8 (k0 = 16kt+4lq is always %4==0)
    int p0v[8], d2v[8], d3v[8];
#pragma unroll
    for (int kt = 0; kt < 8; ++kt) {
        int k0 = kt * 16 + lq * 4;
        int z2 = (k0 >= 60) ? 1 : 0;
        int k0m = k0 - 60 * z2;
        int h2 = k0m / 10;
        int w2 = k0m - 10 * h2;
        p0v[kt] = z2 * 1368 + h2 * 114 - w2;
        d2v[kt] = (w2 == 8) ? 122 : -2;
        d3v[kt] = (w2 == 8) ? 121 : -3;
    }

    for (int qi = 0; qi < 2; ++qi) {
        const int qt = wave + 4 * qi;
        short8 qfr = *(const short8*)(qwh + (size_t)(qt * 16 + lm) * 32 + lq * 8);
        floatx4 sc[8];
#pragma unroll
        for (int kt = 0; kt < 8; ++kt)
            sc[kt] = __builtin_amdgcn_mfma_f32_16x16x32_bf16(kfr[kt], qfr,
                                                             (floatx4){0.f, 0.f, 0.f, 0.f}, 0, 0, 0);
        // earth-position bias + key-padding mask
        int qg = qt * 16 + lm;
        int zl = qg / 60;
        int r2 = qg - zl * 60;
        int hl = r2 / 10;
        int wl = r2 - hl * 10;
        int pbase = zl * 684 + hl * 19 + wl + 9;
        pbase = min(pbase, 797);        // keeps padded queries in-range
#pragma unroll
        for (int kt = 0; kt < 8; ++kt) {
            if (kt == 7 && lq >= 2) {
                sc[kt] = (floatx4){-1e30f, -1e30f, -1e30f, -1e30f};
            } else {
                int base = pbase + p0v[kt];
                sc[kt][0] += blds[base];
                sc[kt][1] += blds[base - 1];
                sc[kt][2] += blds[base + d2v[kt]];
                sc[kt][3] += blds[base + d3v[kt]];
            }
        }
        // softmax over keys: in-lane (32 vals) then across quads
        float mx = -1e30f;
#pragma unroll
        for (int kt = 0; kt < 8; ++kt)
#pragma unroll
            for (int r = 0; r < 4; ++r) mx = fmaxf(mx, sc[kt][r]);
        mx = fmaxf(mx, __shfl_xor(mx, 16, 64));
        mx = fmaxf(mx, __shfl_xor(mx, 32, 64));
        float l = 0.f;
#pragma unroll
        for (int kt = 0; kt < 8; ++kt)
#pragma unroll
            for (int r = 0; r < 4; ++r) {
                float p = __expf(sc[kt][r] - mx);
                sc[kt][r] = p;
                l += p;
            }
        l += __shfl_xor(l, 16, 64);
        l += __shfl_xor(l, 32, 64);
        float inv = 1.f / l;
        // P (normalized, bf16) -> per-wave LDS [query=lm][key], stride 136 shorts
#pragma unroll
        for (int kt = 0; kt < 8; ++kt) {
            uint2 pk;
            pk.x = (unsigned int)f2bf(sc[kt][0] * inv) | ((unsigned int)f2bf(sc[kt][1] * inv) << 16);
            pk.y = (unsigned int)f2bf(sc[kt][2] * inv) | ((unsigned int)f2bf(sc[kt][3] * inv) << 16);
            *(uint2*)(pl + lm * 136 + kt * 16 + lq * 4) = pk;
        }
        // PV: A = P (from LDS), B = V^T rows (contiguous)
        floatx4 oac[2] = {(floatx4){0.f, 0.f, 0.f, 0.f}, (floatx4){0.f, 0.f, 0.f, 0.f}};
#pragma unroll
        for (int ks = 0; ks < 4; ++ks) {
            short8 af = *(const short8*)(pl + lm * 136 + ks * 32 + lq * 8);
#pragma unroll
            for (int ct = 0; ct < 2; ++ct) {
                short8 bf = *(const short8*)(vwh + (size_t)(ct * 16 + lm) * N_TOK + ks * 32 + lq * 8);
                oac[ct] = __builtin_amdgcn_mfma_f32_16x16x32_bf16(af, bf, oac[ct], 0, 0, 0);
            }
        }
        // store in the reference's head-major reshape; skip padded queries
#pragma unroll
        for (int r = 0; r < 4; ++r) {
            int qg2 = qt * 16 + lq * 4 + r;
            if (qg2 < N_TOK) {
                int rq = qg2 / 12;
                int rr = h * 10 + rq;
                int cc = (qg2 - rq * 12) * 32;
#pragma unroll
                for (int ct = 0; ct < 2; ++ct)
                    ao[((size_t)w * N_TOK + rr) * C_DIM + cc + ct * 16 + lm] = f2bf(oac[ct][r]);
            }
        }
    }
}

// -------- K3: proj MFMA GEMM + window reverse --------
__global__ __launch_bounds__(256) void k_proj(const unsigned short* __restrict__ ao,
                                              const unsigned short* __restrict__ wprojT,
                                              const float* __restrict__ bproj,
                                              float* __restrict__ p) {
    __shared__ unsigned short As[128 * 32];
    __shared__ unsigned short Bs[128 * 32];
    const int tid = threadIdx.x;
    const int wave = tid >> 6, lane = tid & 63;
    const int wm = (wave >> 1) << 6, wn = (wave & 1) << 6;
    const int lm = lane & 15, lq = lane >> 4;
    const int m0 = blockIdx.y << 7, n0 = blockIdx.x << 7;
    floatx4 acc[4][4];
#pragma unroll
    for (int i = 0; i < 4; ++i)
#pragma unroll
        for (int j = 0; j < 4; ++j) acc[i][j] = (floatx4){0.f, 0.f, 0.f, 0.f};
    mfma_loop<C_DIM>(ao, wprojT, As, Bs, m0, n0, acc);
#pragma unroll
    for (int i = 0; i < 4; ++i) {
        int rowb = m0 + wm + i * 16 + lq * 4;
        int gg[4];
#pragma unroll
        for (int r = 0; r < 4; ++r) gg[r] = win_to_global(rowb + r);
#pragma unroll
        for (int j = 0; j < 4; ++j) {
            int colg = n0 + wn + j * 16 + lm;
            float bias = bproj[colg];
#pragma unroll
            for (int r = 0; r < 4; ++r)
                p[(size_t)gg[r] * C_DIM + colg] = acc[i][j][r] + bias;
        }
    }
}

// -------- K5: mlp1 MFMA GEMM + exact GELU -> bf16 --------
__global__ __launch_bounds__(256) void k_mlp1(const unsigned short* __restrict__ x1b,
                                              const unsigned short* __restrict__ wm1T,
                                              const float* __restrict__ bm1,
                                              unsigned short* __restrict__ hbuf) {
    __shared__ unsigned short As[128 * 32];
    __shared__ unsigned short Bs[128 * 32];
    const int tid = threadIdx.x;
    const int wave = tid >> 6, lane = tid & 63;
    const int wm = (wave >> 1) << 6, wn = (wave & 1) << 6;
    const int lm = lane & 15, lq = lane >> 4;
    const int m0 = blockIdx.y << 7, n0 = blockIdx.x << 7;
    floatx4 acc[4][4];
#pragma unroll
    for (int i = 0; i < 4; ++i)
#pragma unroll
        for (int j = 0; j < 4; ++j) acc[i][j] = (floatx4){0.f, 0.f, 0.f, 0.f};
    mfma_loop<C_DIM>(x1b, wm1T, As, Bs, m0, n0, acc);
#pragma unroll
    for (int i = 0; i < 4; ++i) {
        int rowb = m0 + wm + i * 16 + lq * 4;
#pragma unroll
        for (int j = 0; j < 4; ++j) {
            int colg = n0 + wn + j * 16 + lm;
            float bias = bm1[colg];
#pragma unroll
            for (int r = 0; r < 4; ++r) {
                float vv = acc[i][j][r] + bias;
                float ge = 0.5f * vv * (1.f + erff(vv * 0.70710678118654752f));
                hbuf[(size_t)(rowb + r) * C4 + colg] = f2bf(ge);
            }
        }
    }
}

// -------- K6: mlp2 MFMA GEMM -> fp32 --------
__global__ __launch_bounds__(256) void k_mlp2(const unsigned short* __restrict__ hbuf,
                                              const unsigned short* __restrict__ wm2T,
                                              const float* __restrict__ bm2,
                                              float* __restrict__ mbuf) {
    __shared__ unsigned short As[128 * 32];
    __shared__ unsigned short Bs[128 * 32];
    const int tid = threadIdx.x;
    const int wave = tid >> 6, lane = tid & 63;
    const int wm = (wave >> 1) << 6, wn = (wave & 1) << 6;
    const int lm = lane & 15, lq = lane >> 4;
    const int m0 = blockIdx.y << 7, n0 = blockIdx.x << 7;
    floatx4 acc[4][4];
#pragma unroll
    for (int i = 0; i < 4; ++i)
#pragma unroll
        for (int j = 0; j < 4; ++j) acc[i][j] = (floatx4){0.f, 0.f, 0.f, 0.f};
    mfma_loop<C4>(hbuf, wm2T, As, Bs, m0, n0, acc);
#pragma unroll
    for (int i = 0; i < 4; ++i) {
        int rowb = m0 + wm + i * 16 + lq * 4;
#pragma unroll
        for (int j = 0; j < 4; ++j) {
            int colg = n0 + wn + j * 16 + lm;
            float bias = bm2[colg];
#pragma unroll
            for (int r = 0; r < 4; ++r)
                mbuf[(size_t)(rowb + r) * C_DIM + colg] = acc[i][j][r] + bias;
        }
    }
}

// -------- K4/K7: out = resid + LayerNorm(src)*g + b  (+ optional bf16 copy) --------
// NOTE: safe when src == outp (each thread reads its 3 elements before writing).
__global__ __launch_bounds__(128) void k_ln_res(const float* __restrict__ src,
                                                const float* __restrict__ resid,
                                                const float* __restrict__ gamma,
                                                const float* __restrict__ beta,
                                                float* __restrict__ outp,
                                                unsigned short* __restrict__ out_bf) {
    const int row = blockIdx.x;
    const int t = threadIdx.x;
    const float* sr = src + (size_t)row * C_DIM;
    float v0 = sr[t], v1 = sr[t + 128], v2 = sr[t + 256];
    __shared__ float rs[128], rq[128];
    rs[t] = v0 + v1 + v2;
    rq[t] = v0 * v0 + v1 * v1 + v2 * v2;
    __syncthreads();
    for (int off = 64; off > 0; off >>= 1) {
        if (t < off) { rs[t] += rs[t + off]; rq[t] += rq[t + off]; }
        __syncthreads();
    }
    float mu = rs[0] * (1.f / 384.f);
    float var = rq[0] * (1.f / 384.f) - mu * mu;
    float rinv = rsqrtf(var + 1e-5f);
    const float* rr = resid + (size_t)row * C_DIM;
    float* orow = outp + (size_t)row * C_DIM;
    float y0 = rr[t]       + (v0 - mu) * rinv * gamma[t]       + beta[t];
    float y1 = rr[t + 128] + (v1 - mu) * rinv * gamma[t + 128] + beta[t + 128];
    float y2 = rr[t + 256] + (v2 - mu) * rinv * gamma[t + 256] + beta[t + 256];
    orow[t] = y0; orow[t + 128] = y1; orow[t + 256] = y2;
    if (out_bf) {
        unsigned short* ob = out_bf + (size_t)row * C_DIM;
        ob[t] = f2bf(y0); ob[t + 128] = f2bf(y1); ob[t + 256] = f2bf(y2);
    }
}

extern "C" void kernel_launch(void* const* d_in, const int* in_sizes, int n_in,
                              void* d_out, int out_size, void* d_ws, size_t ws_size,
                              hipStream_t stream) {
    const float* x     = (const float*)d_in[0];
    const float* wqkv  = (const float*)d_in[1];
    const float* bqkv  = (const float*)d_in[2];
    const float* wproj = (const float*)d_in[3];
    const float* bproj = (const float*)d_in[4];
    const float* btab  = (const float*)d_in[5];
    const float* g1    = (const float*)d_in[6];
    const float* b1    = (const float*)d_in[7];
    const float* g2    = (const float*)d_in[8];
    const float* b2    = (const float*)d_in[9];
    const float* wm1   = (const float*)d_in[10];
    const float* bm1   = (const float*)d_in[11];
    const float* wm2   = (const float*)d_in[12];
    const float* bm2   = (const float*)d_in[13];
    float* outp = (float*)d_out;

    const size_t LC = (size_t)L_TOK * C_DIM;          // elements
    if (ws_size < 8 * LC) return;                     // 212.3 MB
    char* ws = (char*)d_ws;
    const size_t QB = LC * 2;                         // bytes of one bf16 L x C buffer
    unsigned short* qb  = (unsigned short*)ws;                    // [0, QB)
    unsigned short* kb  = (unsigned short*)(ws + QB);             // [QB, 2QB)
    unsigned short* vb  = (unsigned short*)(ws + 2 * QB);         // [2QB, 3QB)  (V^T layout)
    unsigned short* btT = (unsigned short*)(ws + 3 * QB);         // 37.8 MB, dead after attn
    unsigned short* hbuf = (unsigned short*)(ws + 3 * QB);        // 42.5 MB, over btT (dead after attn)
    size_t wof = 3 * QB + (size_t)CHUNK * C4 * 2;                 // weights live past hbuf
    unsigned short* wqkvT = (unsigned short*)(ws + wof);
    unsigned short* wprojT = wqkvT + (size_t)C3 * C_DIM;
    unsigned short* wm1T   = wprojT + (size_t)C_DIM * C_DIM;
    unsigned short* wm2T   = wm1T + (size_t)C_DIM * C4;
    unsigned short* aob = qb;                                     // exact per-query alias of q
    float* proj = (float*)(ws + QB);                              // over k,v (dead after attn)
    float* x1   = proj;                                           // LN1 in-place
    unsigned short* x1b = qb;                                     // over ao (dead after proj)
    unsigned short* xbuf = (unsigned short*)d_out;                // window-permuted bf16 x
                                                                  // (d_out free until MLP tail)

    dim3 tb(32, 8);
    k_wt<<<dim3(C3 / 32, C_DIM / 32), tb, 0, stream>>>(wqkv, wqkvT, C_DIM, C3);
    k_wt<<<dim3(C_DIM / 32, C_DIM / 32), tb, 0, stream>>>(wproj, wprojT, C_DIM, C_DIM);
    k_wt<<<dim3(C4 / 32, C_DIM / 32), tb, 0, stream>>>(wm1, wm1T, C_DIM, C4);
    k_wt<<<dim3(C_DIM / 32, C4 / 32), tb, 0, stream>>>(wm2, wm2T, C4, C_DIM);
    k_bt<<<dim3(WH / 32, (BIAS_ROWS + 31) / 32), tb, 0, stream>>>(btab, btT);

    k_xc<<<dim3(L_TOK / 4), dim3(256), 0, stream>>>(x, xbuf);
    k_qkv<<<dim3(C3 / 128, L_TOK / 128), dim3(256), 0, stream>>>(xbuf, wqkvT, bqkv, qb, kb, vb);
    k_attn<<<dim3(WH), dim3(256), 0, stream>>>(qb, kb, vb, btT, aob);
    k_proj<<<dim3(C_DIM / 128, L_TOK / 128), dim3(256), 0, stream>>>(aob, wprojT, bproj, proj);
    k_ln_res<<<dim3(L_TOK), dim3(128), 0, stream>>>(proj, x, g1, b1, x1, x1b);
    for (int c = 0; c < NCHUNK; ++c) {
        size_t r0 = (size_t)c * CHUNK;
        float* mbuf = outp + r0 * C_DIM;    // mlp2 writes into out; LN runs in place
        k_mlp1<<<dim3(C4 / 128, CHUNK / 128), dim3(256), 0, stream>>>(x1b + r0 * C_DIM, wm1T, bm1, hbuf);
        k_mlp2<<<dim3(C_DIM / 128, CHUNK / 128), dim3(256), 0, stream>>>(hbuf, wm2T, bm2, mbuf);
        k_ln_res<<<dim3(CHUNK), dim3(128), 0, stream>>>(mbuf, x1 + r0 * C_DIM, g2, b2, mbuf, (unsigned short*)nullptr);
    }
    (void)in_sizes; (void)n_in; (void)out_size;
}

// Round 3
// 1089.100 us; speedup vs baseline: 1.1770x; 1.0217x over previous
//
#include <hip/hip_runtime.h>
#include <math.h>

#define L_TOK 69120
#define C_DIM 384
#define C3 1152
#define C4 1536
#define N_TOK 120
#define N_HEAD 12
#define BIAS_ROWS 2736
#define WH 6912
#define CHUNK 13824
#define NCHUNK 5

typedef __attribute__((ext_vector_type(8))) short short8;
typedef __attribute__((ext_vector_type(4))) float floatx4;

__device__ __forceinline__ unsigned short f2bf(float f) {
    union { float f; unsigned int u; } c; c.f = f;
    unsigned int u = c.u;
    return (unsigned short)((u + 0x7fffu + ((u >> 16) & 1u)) >> 16);
}
__device__ __forceinline__ float bf2f(unsigned short s) {
    union { unsigned int u; float f; } c; c.u = ((unsigned int)s) << 16;
    return c.f;
}

__device__ __forceinline__ void gl_lds16(const void* g, void* l) {
    __builtin_amdgcn_global_load_lds((const __attribute__((address_space(1))) unsigned int*)g,
                                     (__attribute__((address_space(3))) unsigned int*)l, 16, 0, 0);
}

// bijective XCD-chunked swizzle (m204): round-robin hw order -> contiguous chunks
__device__ __forceinline__ void xcd_swz(int gx, int nwg, int* bx, int* by) {
    int orig = blockIdx.y * gx + blockIdx.x;
    int q8 = nwg >> 3, r8 = nwg & 7;
    int xcd = orig & 7, lin = orig >> 3;
    int sw = (xcd < r8 ? xcd * (q8 + 1) : r8 * (q8 + 1) + (xcd - r8) * q8) + lin;
    *bx = sw % gx;
    *by = sw / gx;
}

// window-order row m = w_idx*120 + n  ->  global token index
__device__ __forceinline__ int win_to_global(int m) {
    int w_idx = m / N_TOK;
    int n = m - w_idx * N_TOK;
    int zw = w_idx / 144;
    int rem = w_idx - zw * 144;
    int hw = rem / 18;
    int ww = rem - hw * 18;
    int zl = n / 60;
    int r2 = n - zl * 60;
    int hl = r2 / 10;
    int wl = r2 - hl * 10;
    return ((zw * 2 + zl) * 48 + hw * 6 + hl) * 180 + ww * 10 + wl;
}

// -------- weight transpose+convert: W (K x N fp32) -> WT (N x K bf16) --------
// perm=1: within-64 column permutation Pi, so a lane's 4 j-accumulators land on
// 4 consecutive physical output columns (4*lm+j).
__global__ __launch_bounds__(256) void k_wt(const float* __restrict__ W,
                                            unsigned short* __restrict__ WT, int K, int N, int perm) {
    __shared__ float tle[32][33];
    int n0 = blockIdx.x << 5, k0 = blockIdx.y << 5;
    for (int i = threadIdx.y; i < 32; i += 8) {
        int n = n0 + threadIdx.x;
        int src = perm ? ((n & ~63) | ((n & 15) << 2) | ((n >> 4) & 3)) : n;
        tle[i][threadIdx.x] = W[(size_t)(k0 + i) * N + src];
    }
    __syncthreads();
    for (int i = threadIdx.y; i < 32; i += 8)
        WT[(size_t)(n0 + i) * K + k0 + threadIdx.x] = f2bf(tle[threadIdx.x][i]);
}

// -------- bias transpose: (2736 x 6912 fp32) -> (6912 x 2736 bf16) --------
__global__ __launch_bounds__(256) void k_bt(const float* __restrict__ Bsrc,
                                            unsigned short* __restrict__ BTt) {
    __shared__ float tle[32][33];
    int c0 = blockIdx.x << 5;
    int r0 = blockIdx.y << 5;
    for (int i = threadIdx.y; i < 32; i += 8) {
        int r = r0 + i;
        if (r < BIAS_ROWS) tle[i][threadIdx.x] = Bsrc[(size_t)r * WH + c0 + threadIdx.x];
    }
    __syncthreads();
    int rr = r0 + threadIdx.x;
    if (rr < BIAS_ROWS)
        for (int i = threadIdx.y; i < 32; i += 8)
            BTt[(size_t)(c0 + i) * BIAS_ROWS + rr] = f2bf(tle[threadIdx.x][i]);
}

// -------- x -> window-permuted bf16; 8 floats/thread -> one 16B store --------
__global__ __launch_bounds__(256) void k_xc(const float* __restrict__ x,
                                            unsigned short* __restrict__ xb) {
    int gid = blockIdx.x * 256 + threadIdx.x;
    int m = gid / 48;
    int seg = gid - m * 48;
    const float* src = x + (size_t)win_to_global(m) * C_DIM + seg * 8;
    float4 a = *(const float4*)(src);
    float4 b = *(const float4*)(src + 4);
    uint4 o;
    o.x = (unsigned int)f2bf(a.x) | ((unsigned int)f2bf(a.y) << 16);
    o.y = (unsigned int)f2bf(a.z) | ((unsigned int)f2bf(a.w) << 16);
    o.z = (unsigned int)f2bf(b.x) | ((unsigned int)f2bf(b.y) << 16);
    o.w = (unsigned int)f2bf(b.z) | ((unsigned int)f2bf(b.w) << 16);
    *(uint4*)(xb + (size_t)m * C_DIM + seg * 8) = o;
}

// -------- shared MFMA mainloop (bf16 A, bf16 B^T, both via global_load_lds) --------
template <int K>
__device__ __forceinline__ void mfma_loop(const unsigned short* __restrict__ A,
                                          const unsigned short* __restrict__ BT,
                                          unsigned short* As, unsigned short* Bs,
                                          int m0, int n0, floatx4 acc[4][4]) {
    const int tid = threadIdx.x;
    const int wave = tid >> 6, lane = tid & 63;
    const int wm = (wave >> 1) << 6, wn = (wave & 1) << 6;
    const int lm = lane & 15, lq = lane >> 4;
    const int srow = lane >> 2, scol = (lane & 3) << 3;
    const unsigned short* ags = A + (size_t)(m0 + wave * 32 + srow) * K + scol;
    const unsigned short* bgs = BT + (size_t)(n0 + wave * 32 + srow) * K + scol;
    char* lA = (char*)As + wave * 2048;
    char* lB = (char*)Bs + wave * 2048;
    for (int kk = 0; kk < K; kk += 32) {
        gl_lds16(ags + kk, lA);
        gl_lds16(ags + (size_t)16 * K + kk, lA + 1024);
        gl_lds16(bgs + kk, lB);
        gl_lds16(bgs + (size_t)16 * K + kk, lB + 1024);
        __syncthreads();
        short8 af[4], bq[4];
#pragma unroll
        for (int i = 0; i < 4; ++i) af[i] = *(const short8*)(As + (wm + i * 16 + lm) * 32 + lq * 8);
#pragma unroll
        for (int j = 0; j < 4; ++j) bq[j] = *(const short8*)(Bs + (wn + j * 16 + lm) * 32 + lq * 8);
#pragma unroll
        for (int i = 0; i < 4; ++i)
#pragma unroll
            for (int j = 0; j < 4; ++j)
                acc[i][j] = __builtin_amdgcn_mfma_f32_16x16x32_bf16(af[i], bq[j], acc[i][j], 0, 0, 0);
        __syncthreads();
    }
}

// -------- K1: qkv MFMA GEMM; Pi-permuted B, LDS-bounce full-line epilogue --------
// q: (wh, n, d) scaled; k: (wh, n, d); v: TRANSPOSED (wh, d, n)
__global__ __launch_bounds__(256) void k_qkv(const unsigned short* __restrict__ xb,
                                             const unsigned short* __restrict__ wqkvT,
                                             const float* __restrict__ bqkv,
                                             unsigned short* __restrict__ q,
                                             unsigned short* __restrict__ kbuf,
                                             unsigned short* __restrict__ vbuf) {
    __shared__ __align__(16) unsigned short smem[128 * 136];   // 34816 B; As/Bs alias front
    unsigned short* As = smem;
    unsigned short* Bs = smem + 128 * 32;
    const int tid = threadIdx.x;
    int bx, by;
    xcd_swz(9, 9 * (L_TOK / 128), &bx, &by);
    const int m0 = by << 7, n0 = bx << 7;
    const int wave = tid >> 6, lane = tid & 63;
    const int wm = (wave >> 1) << 6, wn = (wave & 1) << 6;
    const int lm = lane & 15, lq = lane >> 4;

    floatx4 acc[4][4];
#pragma unroll
    for (int i = 0; i < 4; ++i)
#pragma unroll
        for (int j = 0; j < 4; ++j) acc[i][j] = (floatx4){0.f, 0.f, 0.f, 0.f};
    mfma_loop<C_DIM>(xb, wqkvT, As, Bs, m0, n0, acc);

    const int sel = bx / 3;   // uniform per block: 0=q 1=k 2=v
    unsigned short* dst = (sel == 0) ? q : (sel == 1) ? kbuf : vbuf;
    const float scl = (sel == 0) ? 0.17677669529663687f : 1.0f;
    float4 b4 = *(const float4*)(bqkv + n0 + wn + 4 * lm);   // 4 consecutive phys cols

    if (sel < 2) {
        // stage row-major [row][136]: lane's 4 j-vals = 4 consecutive phys cols
#pragma unroll
        for (int i = 0; i < 4; ++i)
#pragma unroll
            for (int r = 0; r < 4; ++r) {
                uint2 pk;
                pk.x = (unsigned int)f2bf((acc[i][0][r] + b4.x) * scl) |
                       ((unsigned int)f2bf((acc[i][1][r] + b4.y) * scl) << 16);
                pk.y = (unsigned int)f2bf((acc[i][2][r] + b4.z) * scl) |
                       ((unsigned int)f2bf((acc[i][3][r] + b4.w) * scl) << 16);
                *(uint2*)(smem + (wm + i * 16 + lq * 4 + r) * 136 + wn + 4 * lm) = pk;
            }
        __syncthreads();
#pragma unroll
        for (int it = 0; it < 8; ++it) {
            int s = it * 256 + tid;
            int row = s >> 4, cs = (s & 15) << 3;
            uint4 vv = *(const uint4*)(smem + row * 136 + cs);
            int m = m0 + row;
            int wi = m / N_TOK, nn = m - wi * N_TOK;
            int c2 = n0 + cs - sel * C_DIM;
            int head = c2 >> 5, dd = c2 & 31;
            *(uint4*)(dst + (((size_t)(wi * N_HEAD + head) * N_TOK + nn) << 5) + dd) = vv;
        }
    } else {
        // stage col-major [col][136]: lane's 4 r-vals = 4 consecutive nn
#pragma unroll
        for (int i = 0; i < 4; ++i)
#pragma unroll
            for (int j = 0; j < 4; ++j) {
                float bj = (j == 0) ? b4.x : (j == 1) ? b4.y : (j == 2) ? b4.z : b4.w;
                uint2 pk;
                pk.x = (unsigned int)f2bf(acc[i][j][0] + bj) |
                       ((unsigned int)f2bf(acc[i][j][1] + bj) << 16);
                pk.y = (unsigned int)f2bf(acc[i][j][2] + bj) |
                       ((unsigned int)f2bf(acc[i][j][3] + bj) << 16);
                *(uint2*)(smem + (wn + 4 * lm + j) * 136 + wm + i * 16 + lq * 4) = pk;
            }
        __syncthreads();
#pragma unroll
        for (int it = 0; it < 8; ++it) {
            int s = it * 256 + tid;
            int c = s >> 4, mo = (s & 15) << 3;     // 16 threads sweep one v-row
            uint4 vv = *(const uint4*)(smem + c * 136 + mo);
            int m = m0 + mo;
            int wi = m / N_TOK, nn = m - wi * N_TOK;   // 8-runs never cross window (120%8==0)
            int c2 = n0 + c - 2 * C_DIM;
            int head = c2 >> 5, dd = c2 & 31;
            *(uint4*)(dst + ((size_t)(wi * N_HEAD + head) * 32 + dd) * N_TOK + nn) = vv;
        }
    }
}

// -------- K2: MFMA windowed attention (S^T = K·Q^T trick) --------
__global__ __launch_bounds__(256) void k_attn(const unsigned short* __restrict__ q,
                                              const unsigned short* __restrict__ k,
                                              const unsigned short* __restrict__ vt,
                                              const unsigned short* __restrict__ btabT,
                                              unsigned short* __restrict__ ao) {
    const int wh = blockIdx.x;
    const int w = wh / N_HEAD;
    const int h = wh - w * N_HEAD;
    __shared__ float blds[BIAS_ROWS];
    __shared__ __align__(16) unsigned short plds[4][16 * 136];
    const int tid = threadIdx.x;
    const unsigned short* bptr = btabT + (size_t)wh * BIAS_ROWS;
    for (int i = tid; i < BIAS_ROWS; i += 256) blds[i] = bf2f(bptr[i]);
    __syncthreads();

    const int wave = tid >> 6, lane = tid & 63;
    const int lm = lane & 15, lq = lane >> 4;
    const unsigned short* kwh = k + (size_t)wh * N_TOK * 32;
    const unsigned short* qwh = q + (size_t)wh * N_TOK * 32;
    const unsigned short* vwh = vt + (size_t)wh * 32 * N_TOK;
    unsigned short* pl = plds[wave];

    short8 kfr[8];
#pragma unroll
    for (int kt = 0; kt < 8; ++kt)
        kfr[kt] = *(const short8*)(kwh + (size_t)(kt * 16 + lm) * 32 + lq * 8);

    int p0v[8], d2v[8], d3v[8];
#pragma unroll
    for (int kt = 0; kt < 8; ++kt) {
        int k0 = kt * 16 + lq * 4;
        int z2 = (k0 >= 60) ? 1 : 0;
        int k0m = k0 - 60 * z2;
        int h2 = k0m / 10;
        int w2 = k0m - 10 * h2;
        p0v[kt] = z2 * 1368 + h2 * 114 - w2;
        d2v[kt] = (w2 == 8) ? 122 : -2;
        d3v[kt] = (w2 == 8) ? 121 : -3;
    }

    for (int qi = 0; qi < 2; ++qi) {
        const int qt = wave + 4 * qi;
        short8 qfr = *(const short8*)(qwh + (size_t)(qt * 16 + lm) * 32 + lq * 8);
        floatx4 sc[8];
#pragma unroll
        for (int kt = 0; kt < 8; ++kt)
            sc[kt] = __builtin_amdgcn_mfma_f32_16x16x32_bf16(kfr[kt], qfr,
                                                             (floatx4){0.f, 0.f, 0.f, 0.f}, 0, 0, 0);
        int qg = qt * 16 + lm;
        int zl = qg / 60;
        int r2 = qg - zl * 60;
        int hl = r2 / 10;
        int wl = r2 - hl * 10;
        int pbase = zl * 684 + hl * 19 + wl + 9;
        pbase = min(pbase, 797);
#pragma unroll
        for (int kt = 0; kt < 8; ++kt) {
            if (kt == 7 && lq >= 2) {
                sc[kt] = (floatx4){-1e30f, -1e30f, -1e30f, -1e30f};
            } else {
                int base = pbase + p0v[kt];
                sc[kt][0] += blds[base];
                sc[kt][1] += blds[base - 1];
                sc[kt][2] += blds[base + d2v[kt]];
                sc[kt][3] += blds[base + d3v[kt]];
            }
        }
        float mx = -1e30f;
#pragma unroll
        for (int kt = 0; kt < 8; ++kt)
#pragma unroll
            for (int r = 0; r < 4; ++r) mx = fmaxf(mx, sc[kt][r]);
        mx = fmaxf(mx, __shfl_xor(mx, 16, 64));
        mx = fmaxf(mx, __shfl_xor(mx, 32, 64));
        float l = 0.f;
#pragma unroll
        for (int kt = 0; kt < 8; ++kt)
#pragma unroll
            for (int r = 0; r < 4; ++r) {
                float p = __expf(sc[kt][r] - mx);
                sc[kt][r] = p;
                l += p;
            }
        l += __shfl_xor(l, 16, 64);
        l += __shfl_xor(l, 32, 64);
        float inv = 1.f / l;
#pragma unroll
        for (int kt = 0; kt < 8; ++kt) {
            uint2 pk;
            pk.x = (unsigned int)f2bf(sc[kt][0] * inv) | ((unsigned int)f2bf(sc[kt][1] * inv) << 16);
            pk.y = (unsigned int)f2bf(sc[kt][2] * inv) | ((unsigned int)f2bf(sc[kt][3] * inv) << 16);
            *(uint2*)(pl + lm * 136 + kt * 16 + lq * 4) = pk;
        }
        floatx4 oac[2] = {(floatx4){0.f, 0.f, 0.f, 0.f}, (floatx4){0.f, 0.f, 0.f, 0.f}};
#pragma unroll
        for (int ks = 0; ks < 4; ++ks) {
            short8 af = *(const short8*)(pl + lm * 136 + ks * 32 + lq * 8);
#pragma unroll
            for (int ct = 0; ct < 2; ++ct) {
                short8 bf = *(const short8*)(vwh + (size_t)(ct * 16 + lm) * N_TOK + ks * 32 + lq * 8);
                oac[ct] = __builtin_amdgcn_mfma_f32_16x16x32_bf16(af, bf, oac[ct], 0, 0, 0);
            }
        }
#pragma unroll
        for (int r = 0; r < 4; ++r) {
            int qg2 = qt * 16 + lq * 4 + r;
            if (qg2 < N_TOK) {
                int rq = qg2 / 12;
                int rr = h * 10 + rq;
                int cc = (qg2 - rq * 12) * 32;
#pragma unroll
                for (int ct = 0; ct < 2; ++ct)
                    ao[((size_t)w * N_TOK + rr) * C_DIM + cc + ct * 16 + lm] = f2bf(oac[ct][r]);
            }
        }
    }
}

// -------- K3: proj MFMA GEMM + window reverse (fp32 full-line stores) --------
__global__ __launch_bounds__(256) void k_proj(const unsigned short* __restrict__ ao,
                                              const unsigned short* __restrict__ wprojT,
                                              const float* __restrict__ bproj,
                                              float* __restrict__ p) {
    __shared__ unsigned short As[128 * 32];
    __shared__ unsigned short Bs[128 * 32];
    const int tid = threadIdx.x;
    const int wave = tid >> 6, lane = tid & 63;
    const int wm = (wave >> 1) << 6, wn = (wave & 1) << 6;
    const int lm = lane & 15, lq = lane >> 4;
    int bx, by;
    xcd_swz(3, 3 * (L_TOK / 128), &bx, &by);
    const int m0 = by << 7, n0 = bx << 7;
    floatx4 acc[4][4];
#pragma unroll
    for (int i = 0; i < 4; ++i)
#pragma unroll
        for (int j = 0; j < 4; ++j) acc[i][j] = (floatx4){0.f, 0.f, 0.f, 0.f};
    mfma_loop<C_DIM>(ao, wprojT, As, Bs, m0, n0, acc);
#pragma unroll
    for (int i = 0; i < 4; ++i) {
        int rowb = m0 + wm + i * 16 + lq * 4;
        int gg[4];
#pragma unroll
        for (int r = 0; r < 4; ++r) gg[r] = win_to_global(rowb + r);
#pragma unroll
        for (int j = 0; j < 4; ++j) {
            int colg = n0 + wn + j * 16 + lm;
            float bias = bproj[colg];
#pragma unroll
            for (int r = 0; r < 4; ++r)
                p[(size_t)gg[r] * C_DIM + colg] = acc[i][j][r] + bias;
        }
    }
}

// -------- K5: mlp1 MFMA GEMM + exact GELU; Pi-permuted B + LDS-bounce --------
__global__ __launch_bounds__(256) void k_mlp1(const unsigned short* __restrict__ x1b,
                                              const unsigned short* __restrict__ wm1T,
                                              const float* __restrict__ bm1,
                                              unsigned short* __restrict__ hbuf) {
    __shared__ __align__(16) unsigned short smem[128 * 136];
    unsigned short* As = smem;
    unsigned short* Bs = smem + 128 * 32;
    const int tid = threadIdx.x;
    const int wave = tid >> 6, lane = tid & 63;
    const int wm = (wave >> 1) << 6, wn = (wave & 1) << 6;
    const int lm = lane & 15, lq = lane >> 4;
    int bx, by;
    xcd_swz(12, 12 * (CHUNK / 128), &bx, &by);
    const int m0 = by << 7, n0 = bx << 7;
    floatx4 acc[4][4];
#pragma unroll
    for (int i = 0; i < 4; ++i)
#pragma unroll
        for (int j = 0; j < 4; ++j) acc[i][j] = (floatx4){0.f, 0.f, 0.f, 0.f};
    mfma_loop<C_DIM>(x1b, wm1T, As, Bs, m0, n0, acc);

    float4 b4 = *(const float4*)(bm1 + n0 + wn + 4 * lm);
#pragma unroll
    for (int i = 0; i < 4; ++i)
#pragma unroll
        for (int r = 0; r < 4; ++r) {
            float v0 = acc[i][0][r] + b4.x;
            float v1 = acc[i][1][r] + b4.y;
            float v2 = acc[i][2][r] + b4.z;
            float v3 = acc[i][3][r] + b4.w;
            v0 = 0.5f * v0 * (1.f + erff(v0 * 0.70710678118654752f));
            v1 = 0.5f * v1 * (1.f + erff(v1 * 0.70710678118654752f));
            v2 = 0.5f * v2 * (1.f + erff(v2 * 0.70710678118654752f));
            v3 = 0.5f * v3 * (1.f + erff(v3 * 0.70710678118654752f));
            uint2 pk;
            pk.x = (unsigned int)f2bf(v0) | ((unsigned int)f2bf(v1) << 16);
            pk.y = (unsigned int)f2bf(v2) | ((unsigned int)f2bf(v3) << 16);
            *(uint2*)(smem + (wm + i * 16 + lq * 4 + r) * 136 + wn + 4 * lm) = pk;
        }
    __syncthreads();
#pragma unroll
    for (int it = 0; it < 8; ++it) {
        int s = it * 256 + tid;
        int row = s >> 4, cs = (s & 15) << 3;
        uint4 vv = *(const uint4*)(smem + row * 136 + cs);
        *(uint4*)(hbuf + (size_t)(m0 + row) * C4 + n0 + cs) = vv;
    }
}

// -------- K6: mlp2 MFMA GEMM -> fp32 (full-line stores) --------
__global__ __launch_bounds__(256) void k_mlp2(const unsigned short* __restrict__ hbuf,
                                              const unsigned short* __restrict__ wm2T,
                                              const float* __restrict__ bm2,
                                              float* __restrict__ mbuf) {
    __shared__ unsigned short As[128 * 32];
    __shared__ unsigned short Bs[128 * 32];
    const int tid = threadIdx.x;
    const int wave = tid >> 6, lane = tid & 63;
    const int wm = (wave >> 1) << 6, wn = (wave & 1) << 6;
    const int lm = lane & 15, lq = lane >> 4;
    int bx, by;
    xcd_swz(3, 3 * (CHUNK / 128), &bx, &by);
    const int m0 = by << 7, n0 = bx << 7;
    floatx4 acc[4][4];
#pragma unroll
    for (int i = 0; i < 4; ++i)
#pragma unroll
        for (int j = 0; j < 4; ++j) acc[i][j] = (floatx4){0.f, 0.f, 0.f, 0.f};
    mfma_loop<C4>(hbuf, wm2T, As, Bs, m0, n0, acc);
#pragma unroll
    for (int i = 0; i < 4; ++i) {
        int rowb = m0 + wm + i * 16 + lq * 4;
#pragma unroll
        for (int j = 0; j < 4; ++j) {
            int colg = n0 + wn + j * 16 + lm;
            float bias = bm2[colg];
#pragma unroll
            for (int r = 0; r < 4; ++r)
                mbuf[(size_t)(rowb + r) * C_DIM + colg] = acc[i][j][r] + bias;
        }
    }
}

// -------- K4/K7: out = resid + LayerNorm(src)*g + b  (+ optional bf16 copy) --------
__global__ __launch_bounds__(128) void k_ln_res(const float* __restrict__ src,
                                                const float* __restrict__ resid,
                                                const float* __restrict__ gamma,
                                                const float* __restrict__ beta,
                                                float* __restrict__ outp,
                                                unsigned short* __restrict__ out_bf) {
    const int row = blockIdx.x;
    const int t = threadIdx.x;
    const float* sr = src + (size_t)row * C_DIM;
    float v0 = sr[t], v1 = sr[t + 128], v2 = sr[t + 256];
    __shared__ float rs[128], rq[128];
    rs[t] = v0 + v1 + v2;
    rq[t] = v0 * v0 + v1 * v1 + v2 * v2;
    __syncthreads();
    for (int off = 64; off > 0; off >>= 1) {
        if (t < off) { rs[t] += rs[t + off]; rq[t] += rq[t + off]; }
        __syncthreads();
    }
    float mu = rs[0] * (1.f / 384.f);
    float var = rq[0] * (1.f / 384.f) - mu * mu;
    float rinv = rsqrtf(var + 1e-5f);
    const float* rr = resid + (size_t)row * C_DIM;
    float* orow = outp + (size_t)row * C_DIM;
    float y0 = rr[t]       + (v0 - mu) * rinv * gamma[t]       + beta[t];
    float y1 = rr[t + 128] + (v1 - mu) * rinv * gamma[t + 128] + beta[t + 128];
    float y2 = rr[t + 256] + (v2 - mu) * rinv * gamma[t + 256] + beta[t + 256];
    orow[t] = y0; orow[t + 128] = y1; orow[t + 256] = y2;
    if (out_bf) {
        unsigned short* ob = out_bf + (size_t)row * C_DIM;
        ob[t] = f2bf(y0); ob[t + 128] = f2bf(y1); ob[t + 256] = f2bf(y2);
    }
}

extern "C" void kernel_launch(void* const* d_in, const int* in_sizes, int n_in,
                              void* d_out, int out_size, void* d_ws, size_t ws_size,
                              hipStream_t stream) {
    const float* x     = (const float*)d_in[0];
    const float* wqkv  = (const float*)d_in[1];
    const float* bqkv  = (const float*)d_in[2];
    const float* wproj = (const float*)d_in[3];
    const float* bproj = (const float*)d_in[4];
    const float* btab  = (const float*)d_in[5];
    const float* g1    = (const float*)d_in[6];
    const float* b1    = (const float*)d_in[7];
    const float* g2    = (const float*)d_in[8];
    const float* b2    = (const float*)d_in[9];
    const float* wm1   = (const float*)d_in[10];
    const float* bm1   = (const float*)d_in[11];
    const float* wm2   = (const float*)d_in[12];
    const float* bm2   = (const float*)d_in[13];
    float* outp = (float*)d_out;

    const size_t LC = (size_t)L_TOK * C_DIM;          // elements
    if (ws_size < 8 * LC) return;                     // 212.3 MB
    char* ws = (char*)d_ws;
    const size_t QB = LC * 2;                         // bytes of one bf16 L x C buffer
    unsigned short* qb  = (unsigned short*)ws;                    // [0, QB)
    unsigned short* kb  = (unsigned short*)(ws + QB);             // [QB, 2QB)
    unsigned short* vb  = (unsigned short*)(ws + 2 * QB);         // [2QB, 3QB)  (V^T layout)
    unsigned short* btT = (unsigned short*)(ws + 3 * QB);         // 37.8 MB, dead after attn
    unsigned short* hbuf = (unsigned short*)(ws + 3 * QB);        // 42.5 MB, over btT
    size_t wof = 3 * QB + (size_t)CHUNK * C4 * 2;                 // weights live past hbuf
    unsigned short* wqkvT = (unsigned short*)(ws + wof);
    unsigned short* wprojT = wqkvT + (size_t)C3 * C_DIM;
    unsigned short* wm1T   = wprojT + (size_t)C_DIM * C_DIM;
    unsigned short* wm2T   = wm1T + (size_t)C_DIM * C4;
    unsigned short* aob = qb;                                     // exact per-query alias of q
    float* proj = (float*)(ws + QB);                              // over k,v (dead after attn)
    float* x1   = proj;                                           // LN1 in-place
    unsigned short* x1b = qb;                                     // over ao (dead after proj)
    unsigned short* xbuf = (unsigned short*)d_out;                // window-permuted bf16 x
                                                                  // (d_out free until MLP tail)

    dim3 tb(32, 8);
    k_wt<<<dim3(C3 / 32, C_DIM / 32), tb, 0, stream>>>(wqkv, wqkvT, C_DIM, C3, 1);
    k_wt<<<dim3(C_DIM / 32, C_DIM / 32), tb, 0, stream>>>(wproj, wprojT, C_DIM, C_DIM, 0);
    k_wt<<<dim3(C4 / 32, C_DIM / 32), tb, 0, stream>>>(wm1, wm1T, C_DIM, C4, 1);
    k_wt<<<dim3(C_DIM / 32, C4 / 32), tb, 0, stream>>>(wm2, wm2T, C4, C_DIM, 0);
    k_bt<<<dim3(WH / 32, (BIAS_ROWS + 31) / 32), tb, 0, stream>>>(btab, btT);

    k_xc<<<dim3(L_TOK * 48 / 256), dim3(256), 0, stream>>>(x, xbuf);
    k_qkv<<<dim3(C3 / 128, L_TOK / 128), dim3(256), 0, stream>>>(xbuf, wqkvT, bqkv, qb, kb, vb);
    k_attn<<<dim3(WH), dim3(256), 0, stream>>>(qb, kb, vb, btT, aob);
    k_proj<<<dim3(C_DIM / 128, L_TOK / 128), dim3(256), 0, stream>>>(aob, wprojT, bproj, proj);
    k_ln_res<<<dim3(L_TOK), dim3(128), 0, stream>>>(proj, x, g1, b1, x1, x1b);
    for (int c = 0; c < NCHUNK; ++c) {
        size_t r0 = (size_t)c * CHUNK;
        float* mbuf = outp + r0 * C_DIM;    // mlp2 writes into out; LN runs in place
        k_mlp1<<<dim3(C4 / 128, CHUNK / 128), dim3(256), 0, stream>>>(x1b + r0 * C_DIM, wm1T, bm1, hbuf);
        k_mlp2<<<dim3(C_DIM / 128, CHUNK / 128), dim3(256), 0, stream>>>(hbuf, wm2T, bm2, mbuf);
        k_ln_res<<<dim3(CHUNK), dim3(128), 0, stream>>>(mbuf, x1 + r0 * C_DIM, g2, b2, mbuf, (unsigned short*)nullptr);
    }
    (void)in_sizes; (void)n_in; (void)out_size;
}

// Round 4
// 1056.890 us; speedup vs baseline: 1.2128x; 1.0305x over previous
//
#include <hip/hip_runtime.h>
#include <math.h>

#define L_TOK 69120
#define C_DIM 384
#define C3 1152
#define C4 1536
#define N_TOK 120
#define N_HEAD 12
#define BIAS_ROWS 2736
#define WH 6912
#define CHUNK 13824
#define NCHUNK 5

typedef __attribute__((ext_vector_type(8))) short short8;
typedef __attribute__((ext_vector_type(4))) float floatx4;

__device__ __forceinline__ unsigned short f2bf(float f) {
    union { float f; unsigned int u; } c; c.f = f;
    unsigned int u = c.u;
    return (unsigned short)((u + 0x7fffu + ((u >> 16) & 1u)) >> 16);
}
__device__ __forceinline__ float bf2f(unsigned short s) {
    union { unsigned int u; float f; } c; c.u = ((unsigned int)s) << 16;
    return c.f;
}
// RNE pack of 2 fp32 -> 2 bf16 in one instruction (no builtin on gfx950)
__device__ __forceinline__ unsigned int cvtpk_bf16(float lo, float hi) {
    unsigned int r;
    asm("v_cvt_pk_bf16_f32 %0, %1, %2" : "=v"(r) : "v"(lo), "v"(hi));
    return r;
}

__device__ __forceinline__ void gl_lds16(const void* g, void* l) {
    __builtin_amdgcn_global_load_lds((const __attribute__((address_space(1))) unsigned int*)g,
                                     (__attribute__((address_space(3))) unsigned int*)l, 16, 0, 0);
}

// bijective XCD-chunked swizzle (m204): round-robin hw order -> contiguous chunks
__device__ __forceinline__ void xcd_swz(int gx, int nwg, int* bx, int* by) {
    int orig = blockIdx.y * gx + blockIdx.x;
    int q8 = nwg >> 3, r8 = nwg & 7;
    int xcd = orig & 7, lin = orig >> 3;
    int sw = (xcd < r8 ? xcd * (q8 + 1) : r8 * (q8 + 1) + (xcd - r8) * q8) + lin;
    *bx = sw % gx;
    *by = sw / gx;
}

// window-order row m = w_idx*120 + n  ->  global token index
__device__ __forceinline__ int win_to_global(int m) {
    int w_idx = m / N_TOK;
    int n = m - w_idx * N_TOK;
    int zw = w_idx / 144;
    int rem = w_idx - zw * 144;
    int hw = rem / 18;
    int ww = rem - hw * 18;
    int zl = n / 60;
    int r2 = n - zl * 60;
    int hl = r2 / 10;
    int wl = r2 - hl * 10;
    return ((zw * 2 + zl) * 48 + hw * 6 + hl) * 180 + ww * 10 + wl;
}

// -------- weight transpose+convert: W (K x N fp32) -> WT (N x K bf16) --------
// perm=1: within-64 column permutation Pi, so a lane's 4 j-accumulators land on
// 4 consecutive physical output columns (4*lm+j).
__global__ __launch_bounds__(256) void k_wt(const float* __restrict__ W,
                                            unsigned short* __restrict__ WT, int K, int N, int perm) {
    __shared__ float tle[32][33];
    int n0 = blockIdx.x << 5, k0 = blockIdx.y << 5;
    for (int i = threadIdx.y; i < 32; i += 8) {
        int n = n0 + threadIdx.x;
        int src = perm ? ((n & ~63) | ((n & 15) << 2) | ((n >> 4) & 3)) : n;
        tle[i][threadIdx.x] = W[(size_t)(k0 + i) * N + src];
    }
    __syncthreads();
    for (int i = threadIdx.y; i < 32; i += 8)
        WT[(size_t)(n0 + i) * K + k0 + threadIdx.x] = f2bf(tle[threadIdx.x][i]);
}

// -------- bias transpose: (2736 x 6912 fp32) -> (6912 x 2736 bf16) --------
__global__ __launch_bounds__(256) void k_bt(const float* __restrict__ Bsrc,
                                            unsigned short* __restrict__ BTt) {
    __shared__ float tle[32][33];
    int c0 = blockIdx.x << 5;
    int r0 = blockIdx.y << 5;
    for (int i = threadIdx.y; i < 32; i += 8) {
        int r = r0 + i;
        if (r < BIAS_ROWS) tle[i][threadIdx.x] = Bsrc[(size_t)r * WH + c0 + threadIdx.x];
    }
    __syncthreads();
    int rr = r0 + threadIdx.x;
    if (rr < BIAS_ROWS)
        for (int i = threadIdx.y; i < 32; i += 8)
            BTt[(size_t)(c0 + i) * BIAS_ROWS + rr] = f2bf(tle[threadIdx.x][i]);
}

// -------- x -> window-permuted bf16; 8 floats/thread -> one 16B store --------
__global__ __launch_bounds__(256) void k_xc(const float* __restrict__ x,
                                            unsigned short* __restrict__ xb) {
    int gid = blockIdx.x * 256 + threadIdx.x;
    int m = gid / 48;
    int seg = gid - m * 48;
    const float* src = x + (size_t)win_to_global(m) * C_DIM + seg * 8;
    float4 a = *(const float4*)(src);
    float4 b = *(const float4*)(src + 4);
    uint4 o;
    o.x = (unsigned int)f2bf(a.x) | ((unsigned int)f2bf(a.y) << 16);
    o.y = (unsigned int)f2bf(a.z) | ((unsigned int)f2bf(a.w) << 16);
    o.z = (unsigned int)f2bf(b.x) | ((unsigned int)f2bf(b.y) << 16);
    o.w = (unsigned int)f2bf(b.z) | ((unsigned int)f2bf(b.w) << 16);
    *(uint4*)(xb + (size_t)m * C_DIM + seg * 8) = o;
}

// -------- shared MFMA mainloop: double-buffered LDS, single barrier per K-step.
// S = 16384 shorts (32 KiB): [buf][A:4096 | B:4096]. Stage of tile t+1 is issued
// BEFORE compute of tile t; __syncthreads' vmcnt drain lands after the MFMAs.
template <int K>
__device__ __forceinline__ void mfma_loop(const unsigned short* __restrict__ A,
                                          const unsigned short* __restrict__ BT,
                                          unsigned short* S,
                                          int m0, int n0, floatx4 acc[4][4]) {
    const int tid = threadIdx.x;
    const int wave = tid >> 6, lane = tid & 63;
    const int wm = (wave >> 1) << 6, wn = (wave & 1) << 6;
    const int lm = lane & 15, lq = lane >> 4;
    const int srow = lane >> 2, scol = (lane & 3) << 3;
    const unsigned short* ags = A + (size_t)(m0 + wave * 32 + srow) * K + scol;
    const unsigned short* bgs = BT + (size_t)(n0 + wave * 32 + srow) * K + scol;
    constexpr int NK = K / 32;
    {
        char* lA = (char*)S + wave * 2048;
        char* lB = (char*)(S + 4096) + wave * 2048;
        gl_lds16(ags, lA);
        gl_lds16(ags + (size_t)16 * K, lA + 1024);
        gl_lds16(bgs, lB);
        gl_lds16(bgs + (size_t)16 * K, lB + 1024);
    }
    __syncthreads();
#pragma unroll 2
    for (int t = 0; t < NK; ++t) {
        if (t + 1 < NK) {
            const int nxt = (t + 1) & 1;
            const int kk = (t + 1) * 32;
            char* lA = (char*)(S + nxt * 8192) + wave * 2048;
            char* lB = (char*)(S + nxt * 8192 + 4096) + wave * 2048;
            gl_lds16(ags + kk, lA);
            gl_lds16(ags + (size_t)16 * K + kk, lA + 1024);
            gl_lds16(bgs + kk, lB);
            gl_lds16(bgs + (size_t)16 * K + kk, lB + 1024);
        }
        const unsigned short* As = S + (t & 1) * 8192;
        const unsigned short* Bs = As + 4096;
        short8 af[4], bq[4];
#pragma unroll
        for (int i = 0; i < 4; ++i) af[i] = *(const short8*)(As + (wm + i * 16 + lm) * 32 + lq * 8);
#pragma unroll
        for (int j = 0; j < 4; ++j) bq[j] = *(const short8*)(Bs + (wn + j * 16 + lm) * 32 + lq * 8);
#pragma unroll
        for (int i = 0; i < 4; ++i)
#pragma unroll
            for (int j = 0; j < 4; ++j)
                acc[i][j] = __builtin_amdgcn_mfma_f32_16x16x32_bf16(af[i], bq[j], acc[i][j], 0, 0, 0);
        __syncthreads();
    }
}

// -------- K1: qkv MFMA GEMM; Pi-permuted B, LDS-bounce full-line epilogue --------
// q: (wh, n, d) scaled; k: (wh, n, d); v: TRANSPOSED (wh, d, n)
__global__ __launch_bounds__(256) void k_qkv(const unsigned short* __restrict__ xb,
                                             const unsigned short* __restrict__ wqkvT,
                                             const float* __restrict__ bqkv,
                                             unsigned short* __restrict__ q,
                                             unsigned short* __restrict__ kbuf,
                                             unsigned short* __restrict__ vbuf) {
    __shared__ __align__(16) unsigned short smem[128 * 136];   // 34816 B; mainloop uses first 32768
    const int tid = threadIdx.x;
    int bx, by;
    xcd_swz(9, 9 * (L_TOK / 128), &bx, &by);
    const int m0 = by << 7, n0 = bx << 7;
    const int wave = tid >> 6, lane = tid & 63;
    const int wm = (wave >> 1) << 6, wn = (wave & 1) << 6;
    const int lm = lane & 15, lq = lane >> 4;

    floatx4 acc[4][4];
#pragma unroll
    for (int i = 0; i < 4; ++i)
#pragma unroll
        for (int j = 0; j < 4; ++j) acc[i][j] = (floatx4){0.f, 0.f, 0.f, 0.f};
    mfma_loop<C_DIM>(xb, wqkvT, smem, m0, n0, acc);

    const int sel = bx / 3;   // uniform per block: 0=q 1=k 2=v
    unsigned short* dst = (sel == 0) ? q : (sel == 1) ? kbuf : vbuf;
    const float scl = (sel == 0) ? 0.17677669529663687f : 1.0f;
    float4 b4 = *(const float4*)(bqkv + n0 + wn + 4 * lm);   // 4 consecutive phys cols

    if (sel < 2) {
        // stage row-major [row][136]: lane's 4 j-vals = 4 consecutive phys cols
#pragma unroll
        for (int i = 0; i < 4; ++i)
#pragma unroll
            for (int r = 0; r < 4; ++r) {
                uint2 pk;
                pk.x = (unsigned int)f2bf((acc[i][0][r] + b4.x) * scl) |
                       ((unsigned int)f2bf((acc[i][1][r] + b4.y) * scl) << 16);
                pk.y = (unsigned int)f2bf((acc[i][2][r] + b4.z) * scl) |
                       ((unsigned int)f2bf((acc[i][3][r] + b4.w) * scl) << 16);
                *(uint2*)(smem + (wm + i * 16 + lq * 4 + r) * 136 + wn + 4 * lm) = pk;
            }
        __syncthreads();
#pragma unroll
        for (int it = 0; it < 8; ++it) {
            int s = it * 256 + tid;
            int row = s >> 4, cs = (s & 15) << 3;
            uint4 vv = *(const uint4*)(smem + row * 136 + cs);
            int m = m0 + row;
            int wi = m / N_TOK, nn = m - wi * N_TOK;
            int c2 = n0 + cs - sel * C_DIM;
            int head = c2 >> 5, dd = c2 & 31;
            *(uint4*)(dst + (((size_t)(wi * N_HEAD + head) * N_TOK + nn) << 5) + dd) = vv;
        }
    } else {
        // stage col-major [col][136]: lane's 4 r-vals = 4 consecutive nn
#pragma unroll
        for (int i = 0; i < 4; ++i)
#pragma unroll
            for (int j = 0; j < 4; ++j) {
                float bj = (j == 0) ? b4.x : (j == 1) ? b4.y : (j == 2) ? b4.z : b4.w;
                uint2 pk;
                pk.x = (unsigned int)f2bf(acc[i][j][0] + bj) |
                       ((unsigned int)f2bf(acc[i][j][1] + bj) << 16);
                pk.y = (unsigned int)f2bf(acc[i][j][2] + bj) |
                       ((unsigned int)f2bf(acc[i][j][3] + bj) << 16);
                *(uint2*)(smem + (wn + 4 * lm + j) * 136 + wm + i * 16 + lq * 4) = pk;
            }
        __syncthreads();
#pragma unroll
        for (int it = 0; it < 8; ++it) {
            int s = it * 256 + tid;
            int c = s >> 4, mo = (s & 15) << 3;     // 16 threads sweep one v-row
            uint4 vv = *(const uint4*)(smem + c * 136 + mo);
            int m = m0 + mo;
            int wi = m / N_TOK, nn = m - wi * N_TOK;   // 8-runs never cross window (120%8==0)
            int c2 = n0 + c - 2 * C_DIM;
            int head = c2 >> 5, dd = c2 & 31;
            *(uint4*)(dst + ((size_t)(wi * N_HEAD + head) * 32 + dd) * N_TOK + nn) = vv;
        }
    }
}

// -------- K2: MFMA windowed attention (S^T = K·Q^T trick) --------
// cvt_pk P-pack, deferred 1/l normalize, exp2 softmax, LDS-staged coalesced output
__global__ __launch_bounds__(256) void k_attn(const unsigned short* __restrict__ q,
                                              const unsigned short* __restrict__ k,
                                              const unsigned short* __restrict__ vt,
                                              const unsigned short* __restrict__ btabT,
                                              unsigned short* __restrict__ ao) {
    const int wh = blockIdx.x;
    const int w = wh / N_HEAD;
    const int h = wh - w * N_HEAD;
    __shared__ float blds[BIAS_ROWS];
    __shared__ __align__(16) unsigned short plds[4][16 * 136];
    __shared__ __align__(16) unsigned short oq[120 * 40];      // head's [query][d] output tile
    const int tid = threadIdx.x;
    const unsigned short* bptr = btabT + (size_t)wh * BIAS_ROWS;
    for (int i = tid; i < BIAS_ROWS; i += 256) blds[i] = bf2f(bptr[i]);
    __syncthreads();

    const int wave = tid >> 6, lane = tid & 63;
    const int lm = lane & 15, lq = lane >> 4;
    const unsigned short* kwh = k + (size_t)wh * N_TOK * 32;
    const unsigned short* qwh = q + (size_t)wh * N_TOK * 32;
    const unsigned short* vwh = vt + (size_t)wh * 32 * N_TOK;
    unsigned short* pl = plds[wave];

    short8 kfr[8];
#pragma unroll
    for (int kt = 0; kt < 8; ++kt)
        kfr[kt] = *(const short8*)(kwh + (size_t)(kt * 16 + lm) * 32 + lq * 8);

    int p0v[8], d2v[8], d3v[8];
#pragma unroll
    for (int kt = 0; kt < 8; ++kt) {
        int k0 = kt * 16 + lq * 4;
        int z2 = (k0 >= 60) ? 1 : 0;
        int k0m = k0 - 60 * z2;
        int h2 = k0m / 10;
        int w2 = k0m - 10 * h2;
        p0v[kt] = z2 * 1368 + h2 * 114 - w2;
        d2v[kt] = (w2 == 8) ? 122 : -2;
        d3v[kt] = (w2 == 8) ? 121 : -3;
    }

    for (int qi = 0; qi < 2; ++qi) {
        const int qt = wave + 4 * qi;
        short8 qfr = *(const short8*)(qwh + (size_t)(qt * 16 + lm) * 32 + lq * 8);
        floatx4 sc[8];
#pragma unroll
        for (int kt = 0; kt < 8; ++kt)
            sc[kt] = __builtin_amdgcn_mfma_f32_16x16x32_bf16(kfr[kt], qfr,
                                                             (floatx4){0.f, 0.f, 0.f, 0.f}, 0, 0, 0);
        int qg = qt * 16 + lm;
        int zl = qg / 60;
        int r2 = qg - zl * 60;
        int hl = r2 / 10;
        int wl = r2 - hl * 10;
        int pbase = zl * 684 + hl * 19 + wl + 9;
        pbase = min(pbase, 797);
#pragma unroll
        for (int kt = 0; kt < 8; ++kt) {
            if (kt == 7 && lq >= 2) {
                sc[kt] = (floatx4){-1e30f, -1e30f, -1e30f, -1e30f};
            } else {
                int base = pbase + p0v[kt];
                sc[kt][0] += blds[base];
                sc[kt][1] += blds[base - 1];
                sc[kt][2] += blds[base + d2v[kt]];
                sc[kt][3] += blds[base + d3v[kt]];
            }
        }
        float mx = -1e30f;
#pragma unroll
        for (int kt = 0; kt < 8; ++kt)
#pragma unroll
            for (int r = 0; r < 4; ++r) mx = fmaxf(mx, sc[kt][r]);
        mx = fmaxf(mx, __shfl_xor(mx, 16, 64));
        mx = fmaxf(mx, __shfl_xor(mx, 32, 64));
        const float mxs = mx * 1.44269504f;
        float l = 0.f;
#pragma unroll
        for (int kt = 0; kt < 8; ++kt)
#pragma unroll
            for (int r = 0; r < 4; ++r) {
                float p = exp2f(fmaf(sc[kt][r], 1.44269504f, -mxs));
                sc[kt][r] = p;
                l += p;
            }
        l += __shfl_xor(l, 16, 64);
        l += __shfl_xor(l, 32, 64);
        float inv = 1.f / l;
        // unnormalized P (bf16) -> per-wave LDS [query=lm][key], stride 136 shorts
#pragma unroll
        for (int kt = 0; kt < 8; ++kt) {
            uint2 pk;
            pk.x = cvtpk_bf16(sc[kt][0], sc[kt][1]);
            pk.y = cvtpk_bf16(sc[kt][2], sc[kt][3]);
            *(uint2*)(pl + lm * 136 + kt * 16 + lq * 4) = pk;
        }
        // PV: A = P (from LDS), B = V^T rows (contiguous)
        floatx4 oac[2] = {(floatx4){0.f, 0.f, 0.f, 0.f}, (floatx4){0.f, 0.f, 0.f, 0.f}};
#pragma unroll
        for (int ks = 0; ks < 4; ++ks) {
            short8 af = *(const short8*)(pl + lm * 136 + ks * 32 + lq * 8);
#pragma unroll
            for (int ct = 0; ct < 2; ++ct) {
                short8 bf = *(const short8*)(vwh + (size_t)(ct * 16 + lm) * N_TOK + ks * 32 + lq * 8);
                oac[ct] = __builtin_amdgcn_mfma_f32_16x16x32_bf16(af, bf, oac[ct], 0, 0, 0);
            }
        }
        // normalize with the owning query's 1/l (shfl) and stage into oq
#pragma unroll
        for (int r = 0; r < 4; ++r) {
            float ir = __shfl(inv, lq * 4 + r, 16);
            int qg2 = qt * 16 + lq * 4 + r;
            if (qg2 < N_TOK) {
                unsigned int u = cvtpk_bf16(oac[0][r] * ir, oac[1][r] * ir);
                oq[qg2 * 40 + lm] = (unsigned short)u;
                oq[qg2 * 40 + 16 + lm] = (unsigned short)(u >> 16);
            }
        }
    }
    __syncthreads();
    // write the head's 10 contiguous ao rows (10 x 384 shorts) with full-line uint4s
    const size_t obase = ((size_t)w * N_TOK + h * 10) * C_DIM;
    for (int idx = tid; idx < 480; idx += 256) {
        int o0 = idx << 3;
        int rq = o0 / 384;
        int c = o0 - rq * 384;
        int ql = c >> 5, d0 = c & 31;
        uint4 vv = *(const uint4*)(oq + (rq * 12 + ql) * 40 + d0);
        *(uint4*)(ao + obase + o0) = vv;
    }
}

// -------- K3: proj MFMA GEMM + window reverse (fp32 full-line stores) --------
__global__ __launch_bounds__(256) void k_proj(const unsigned short* __restrict__ ao,
                                              const unsigned short* __restrict__ wprojT,
                                              const float* __restrict__ bproj,
                                              float* __restrict__ p) {
    __shared__ __align__(16) unsigned short S[16384];
    const int tid = threadIdx.x;
    const int wave = tid >> 6, lane = tid & 63;
    const int wm = (wave >> 1) << 6, wn = (wave & 1) << 6;
    const int lm = lane & 15, lq = lane >> 4;
    int bx, by;
    xcd_swz(3, 3 * (L_TOK / 128), &bx, &by);
    const int m0 = by << 7, n0 = bx << 7;
    floatx4 acc[4][4];
#pragma unroll
    for (int i = 0; i < 4; ++i)
#pragma unroll
        for (int j = 0; j < 4; ++j) acc[i][j] = (floatx4){0.f, 0.f, 0.f, 0.f};
    mfma_loop<C_DIM>(ao, wprojT, S, m0, n0, acc);
#pragma unroll
    for (int i = 0; i < 4; ++i) {
        int rowb = m0 + wm + i * 16 + lq * 4;
        int gg[4];
#pragma unroll
        for (int r = 0; r < 4; ++r) gg[r] = win_to_global(rowb + r);
#pragma unroll
        for (int j = 0; j < 4; ++j) {
            int colg = n0 + wn + j * 16 + lm;
            float bias = bproj[colg];
#pragma unroll
            for (int r = 0; r < 4; ++r)
                p[(size_t)gg[r] * C_DIM + colg] = acc[i][j][r] + bias;
        }
    }
}

// -------- K5: mlp1 MFMA GEMM + exact GELU; Pi-permuted B + LDS-bounce --------
__global__ __launch_bounds__(256) void k_mlp1(const unsigned short* __restrict__ x1b,
                                              const unsigned short* __restrict__ wm1T,
                                              const float* __restrict__ bm1,
                                              unsigned short* __restrict__ hbuf) {
    __shared__ __align__(16) unsigned short smem[128 * 136];
    const int tid = threadIdx.x;
    const int wave = tid >> 6, lane = tid & 63;
    const int wm = (wave >> 1) << 6, wn = (wave & 1) << 6;
    const int lm = lane & 15, lq = lane >> 4;
    int bx, by;
    xcd_swz(12, 12 * (CHUNK / 128), &bx, &by);
    const int m0 = by << 7, n0 = bx << 7;
    floatx4 acc[4][4];
#pragma unroll
    for (int i = 0; i < 4; ++i)
#pragma unroll
        for (int j = 0; j < 4; ++j) acc[i][j] = (floatx4){0.f, 0.f, 0.f, 0.f};
    mfma_loop<C_DIM>(x1b, wm1T, smem, m0, n0, acc);

    float4 b4 = *(const float4*)(bm1 + n0 + wn + 4 * lm);
#pragma unroll
    for (int i = 0; i < 4; ++i)
#pragma unroll
        for (int r = 0; r < 4; ++r) {
            float v0 = acc[i][0][r] + b4.x;
            float v1 = acc[i][1][r] + b4.y;
            float v2 = acc[i][2][r] + b4.z;
            float v3 = acc[i][3][r] + b4.w;
            v0 = 0.5f * v0 * (1.f + erff(v0 * 0.70710678118654752f));
            v1 = 0.5f * v1 * (1.f + erff(v1 * 0.70710678118654752f));
            v2 = 0.5f * v2 * (1.f + erff(v2 * 0.70710678118654752f));
            v3 = 0.5f * v3 * (1.f + erff(v3 * 0.70710678118654752f));
            uint2 pk;
            pk.x = (unsigned int)f2bf(v0) | ((unsigned int)f2bf(v1) << 16);
            pk.y = (unsigned int)f2bf(v2) | ((unsigned int)f2bf(v3) << 16);
            *(uint2*)(smem + (wm + i * 16 + lq * 4 + r) * 136 + wn + 4 * lm) = pk;
        }
    __syncthreads();
#pragma unroll
    for (int it = 0; it < 8; ++it) {
        int s = it * 256 + tid;
        int row = s >> 4, cs = (s & 15) << 3;
        uint4 vv = *(const uint4*)(smem + row * 136 + cs);
        *(uint4*)(hbuf + (size_t)(m0 + row) * C4 + n0 + cs) = vv;
    }
}

// -------- K6: mlp2 MFMA GEMM -> fp32 (full-line stores) --------
__global__ __launch_bounds__(256) void k_mlp2(const unsigned short* __restrict__ hbuf,
                                              const unsigned short* __restrict__ wm2T,
                                              const float* __restrict__ bm2,
                                              float* __restrict__ mbuf) {
    __shared__ __align__(16) unsigned short S[16384];
    const int tid = threadIdx.x;
    const int wave = tid >> 6, lane = tid & 63;
    const int wm = (wave >> 1) << 6, wn = (wave & 1) << 6;
    const int lm = lane & 15, lq = lane >> 4;
    int bx, by;
    xcd_swz(3, 3 * (CHUNK / 128), &bx, &by);
    const int m0 = by << 7, n0 = bx << 7;
    floatx4 acc[4][4];
#pragma unroll
    for (int i = 0; i < 4; ++i)
#pragma unroll
        for (int j = 0; j < 4; ++j) acc[i][j] = (floatx4){0.f, 0.f, 0.f, 0.f};
    mfma_loop<C4>(hbuf, wm2T, S, m0, n0, acc);
#pragma unroll
    for (int i = 0; i < 4; ++i) {
        int rowb = m0 + wm + i * 16 + lq * 4;
#pragma unroll
        for (int j = 0; j < 4; ++j) {
            int colg = n0 + wn + j * 16 + lm;
            float bias = bm2[colg];
#pragma unroll
            for (int r = 0; r < 4; ++r)
                mbuf[(size_t)(rowb + r) * C_DIM + colg] = acc[i][j][r] + bias;
        }
    }
}

// -------- K4/K7: out = resid + LayerNorm(src)*g + b  (+ optional bf16 copy) --------
__global__ __launch_bounds__(128) void k_ln_res(const float* __restrict__ src,
                                                const float* __restrict__ resid,
                                                const float* __restrict__ gamma,
                                                const float* __restrict__ beta,
                                                float* __restrict__ outp,
                                                unsigned short* __restrict__ out_bf) {
    const int row = blockIdx.x;
    const int t = threadIdx.x;
    const float* sr = src + (size_t)row * C_DIM;
    float v0 = sr[t], v1 = sr[t + 128], v2 = sr[t + 256];
    __shared__ float rs[128], rq[128];
    rs[t] = v0 + v1 + v2;
    rq[t] = v0 * v0 + v1 * v1 + v2 * v2;
    __syncthreads();
    for (int off = 64; off > 0; off >>= 1) {
        if (t < off) { rs[t] += rs[t + off]; rq[t] += rq[t + off]; }
        __syncthreads();
    }
    float mu = rs[0] * (1.f / 384.f);
    float var = rq[0] * (1.f / 384.f) - mu * mu;
    float rinv = rsqrtf(var + 1e-5f);
    const float* rr = resid + (size_t)row * C_DIM;
    float* orow = outp + (size_t)row * C_DIM;
    float y0 = rr[t]       + (v0 - mu) * rinv * gamma[t]       + beta[t];
    float y1 = rr[t + 128] + (v1 - mu) * rinv * gamma[t + 128] + beta[t + 128];
    float y2 = rr[t + 256] + (v2 - mu) * rinv * gamma[t + 256] + beta[t + 256];
    orow[t] = y0; orow[t + 128] = y1; orow[t + 256] = y2;
    if (out_bf) {
        unsigned short* ob = out_bf + (size_t)row * C_DIM;
        ob[t] = f2bf(y0); ob[t + 128] = f2bf(y1); ob[t + 256] = f2bf(y2);
    }
}

extern "C" void kernel_launch(void* const* d_in, const int* in_sizes, int n_in,
                              void* d_out, int out_size, void* d_ws, size_t ws_size,
                              hipStream_t stream) {
    const float* x     = (const float*)d_in[0];
    const float* wqkv  = (const float*)d_in[1];
    const float* bqkv  = (const float*)d_in[2];
    const float* wproj = (const float*)d_in[3];
    const float* bproj = (const float*)d_in[4];
    const float* btab  = (const float*)d_in[5];
    const float* g1    = (const float*)d_in[6];
    const float* b1    = (const float*)d_in[7];
    const float* g2    = (const float*)d_in[8];
    const float* b2    = (const float*)d_in[9];
    const float* wm1   = (const float*)d_in[10];
    const float* bm1   = (const float*)d_in[11];
    const float* wm2   = (const float*)d_in[12];
    const float* bm2   = (const float*)d_in[13];
    float* outp = (float*)d_out;

    const size_t LC = (size_t)L_TOK * C_DIM;          // elements
    if (ws_size < 8 * LC) return;                     // 212.3 MB
    char* ws = (char*)d_ws;
    const size_t QB = LC * 2;                         // bytes of one bf16 L x C buffer
    unsigned short* qb  = (unsigned short*)ws;                    // [0, QB)
    unsigned short* kb  = (unsigned short*)(ws + QB);             // [QB, 2QB)
    unsigned short* vb  = (unsigned short*)(ws + 2 * QB);         // [2QB, 3QB)  (V^T layout)
    unsigned short* btT = (unsigned short*)(ws + 3 * QB);         // 37.8 MB, dead after attn
    unsigned short* hbuf = (unsigned short*)(ws + 3 * QB);        // 42.5 MB, over btT
    size_t wof = 3 * QB + (size_t)CHUNK * C4 * 2;                 // weights live past hbuf
    unsigned short* wqkvT = (unsigned short*)(ws + wof);
    unsigned short* wprojT = wqkvT + (size_t)C3 * C_DIM;
    unsigned short* wm1T   = wprojT + (size_t)C_DIM * C_DIM;
    unsigned short* wm2T   = wm1T + (size_t)C_DIM * C4;
    unsigned short* aob = qb;                                     // exact per-query alias of q
    float* proj = (float*)(ws + QB);                              // over k,v (dead after attn)
    float* x1   = proj;                                           // LN1 in-place
    unsigned short* x1b = qb;                                     // over ao (dead after proj)
    unsigned short* xbuf = (unsigned short*)d_out;                // window-permuted bf16 x
                                                                  // (d_out free until MLP tail)

    dim3 tb(32, 8);
    k_wt<<<dim3(C3 / 32, C_DIM / 32), tb, 0, stream>>>(wqkv, wqkvT, C_DIM, C3, 1);
    k_wt<<<dim3(C_DIM / 32, C_DIM / 32), tb, 0, stream>>>(wproj, wprojT, C_DIM, C_DIM, 0);
    k_wt<<<dim3(C4 / 32, C_DIM / 32), tb, 0, stream>>>(wm1, wm1T, C_DIM, C4, 1);
    k_wt<<<dim3(C_DIM / 32, C4 / 32), tb, 0, stream>>>(wm2, wm2T, C4, C_DIM, 0);
    k_bt<<<dim3(WH / 32, (BIAS_ROWS + 31) / 32), tb, 0, stream>>>(btab, btT);

    k_xc<<<dim3(L_TOK * 48 / 256), dim3(256), 0, stream>>>(x, xbuf);
    k_qkv<<<dim3(C3 / 128, L_TOK / 128), dim3(256), 0, stream>>>(xbuf, wqkvT, bqkv, qb, kb, vb);
    k_attn<<<dim3(WH), dim3(256), 0, stream>>>(qb, kb, vb, btT, aob);
    k_proj<<<dim3(C_DIM / 128, L_TOK / 128), dim3(256), 0, stream>>>(aob, wprojT, bproj, proj);
    k_ln_res<<<dim3(L_TOK), dim3(128), 0, stream>>>(proj, x, g1, b1, x1, x1b);
    for (int c = 0; c < NCHUNK; ++c) {
        size_t r0 = (size_t)c * CHUNK;
        float* mbuf = outp + r0 * C_DIM;    // mlp2 writes into out; LN runs in place
        k_mlp1<<<dim3(C4 / 128, CHUNK / 128), dim3(256), 0, stream>>>(x1b + r0 * C_DIM, wm1T, bm1, hbuf);
        k_mlp2<<<dim3(C_DIM / 128, CHUNK / 128), dim3(256), 0, stream>>>(hbuf, wm2T, bm2, mbuf);
        k_ln_res<<<dim3(CHUNK), dim3(128), 0, stream>>>(mbuf, x1 + r0 * C_DIM, g2, b2, mbuf, (unsigned short*)nullptr);
    }
    (void)in_sizes; (void)n_in; (void)out_size;
}